// Round 9
// baseline (185.780 us; speedup 1.0000x reference)
//
#include <hip/hip_runtime.h>
#include <math.h>

// Problem: images [64,256,256] f32 -> patches [16384][256] f32 (identity perm)
//          tokens [16384] = argmin_v ||patch - vocab[v]||^2, vocab [4096][256] f32
#define PS      16
#define D       256
#define V       4096
#define M       16384
#define NSPLIT  64              // V / 64 column groups (per-wave partials)
#define PAIR_CAP 1048576
// Scores packed as u32 keys: q = (u32)((s + 1024) * 512)  (20 bits), key =
// (q << 12) | col. min() on keys = argmin with lowest-index tie-break.
// fp16 score-diff error sigma ~3e-2; QMARGIN 130 quanta (=0.254) is ~8 sigma
// incl. trunc slack -> P(true-argmin excluded) negligible. Flagged (~4%)
// get exact fp64 on a candidate set provably containing the argmin.
#define QMARGIN 130

typedef _Float16 half8 __attribute__((ext_vector_type(8)));
typedef _Float16 half4 __attribute__((ext_vector_type(4)));
typedef float    f32x4 __attribute__((ext_vector_type(4)));

__device__ __forceinline__ void gload_lds16(const void* g, void* l) {
  __builtin_amdgcn_global_load_lds(
      (const __attribute__((address_space(1))) unsigned int*)g,
      (__attribute__((address_space(3))) unsigned int*)l, 16, 0, 0);
}

// ---------------------------------------------------------------------------
// Kernel 1: fused prep. Blocks [0,4096): patchify (float4) + fp16 copy.
// Blocks [4096,5120): vocab fp16 copy + v2. Block 0 zeros pair counter.
// ---------------------------------------------------------------------------
__global__ __launch_bounds__(256) void prep_kernel(
    const float* __restrict__ img, const float* __restrict__ vocab,
    float* __restrict__ outp, _Float16* __restrict__ Ah,
    _Float16* __restrict__ Vh, float* __restrict__ v2,
    int* __restrict__ paircount) {
  if (blockIdx.x < 4096) {
    if (blockIdx.x == 0 && threadIdx.x == 0) *paircount = 0;
    const int t  = blockIdx.x * 256 + threadIdx.x;   // M*D/4 threads
    const int o4 = t << 2;
    const int b   = o4 >> 16;
    const int rem = o4 & 65535;
    const int n   = rem >> 8;
    const int d   = rem & 255;
    const int py = n >> 4, px = n & 15, i = d >> 4, j = d & 15;
    const float4 v = *(const float4*)(img + (b << 16) + ((py * PS + i) << 8) + px * PS + j);
    *(float4*)(outp + o4) = v;
    half4 h = { (_Float16)v.x, (_Float16)v.y, (_Float16)v.z, (_Float16)v.w };
    *(half4*)(Ah + o4) = h;
  } else {
    const int gtid = (blockIdx.x - 4096) * 256 + threadIdx.x;
    const int row  = gtid >> 6;
    const int lane = gtid & 63;
    const float4 v = *(const float4*)(vocab + (size_t)row * D + (lane << 2));
    half4 h = { (_Float16)v.x, (_Float16)v.y, (_Float16)v.z, (_Float16)v.w };
    *(half4*)(Vh + (size_t)row * D + (lane << 2)) = h;
    float s = v.x * v.x + v.y * v.y + v.z * v.z + v.w * v.w;
    #pragma unroll
    for (int off = 32; off > 0; off >>= 1) s += __shfl_down(s, off);
    if (lane == 0) v2[row] = s;
  }
}

// ---------------------------------------------------------------------------
// Kernel 2: fp16 MFMA score GEMM, spill-free, 2-stage software pipeline.
// Block = 64 rows x 256 cols; wave = 64 rows x 64 cols (acc[4][4], 128 MFMA).
// A tile (64x256, 32KB) LDS-resident via swizzled global_load_lds, ONE
// barrier. B fragments direct global->VGPR (16B/lane, Vh 2MB L2-resident),
// prefetched one kt ahead (R8 lesson: the serial load->wait->MFMA chain was
// the limiter; R6 lesson: bound the unroll or the scheduler spills).
// Output: per-wave (64-col-group) top-2 packed keys -> pk[NSPLIT=64][M];
// no cross-wave LDS merge needed.
// ---------------------------------------------------------------------------
__global__ __launch_bounds__(256, 3) void gemm_score_kernel(
    const _Float16* __restrict__ Ah,   // [M][256]
    const _Float16* __restrict__ Vh,   // [V][256]
    const float* __restrict__ v2,
    unsigned* __restrict__ pk1, unsigned* __restrict__ pk2) {
  __shared__ __align__(16) _Float16 Af[8 * 64 * 32];  // [kt][row][32] = 32 KB

  const int tid  = threadIdx.x;
  const int lane = tid & 63;
  const int wid  = tid >> 6;
  const int row0 = blockIdx.x * 64;
  const int sp   = blockIdx.y;              // col split 0..15 (256 cols)
  const int col0 = sp * 256 + wid * 64;     // this wave's 64 cols
  const int grp  = sp * 4 + wid;            // global 64-col group id

  // ---- stage A tile once (8 gloads/wave, one barrier) ----
  // global addr carries the XOR swizzle; HW writes LDS at base + lane*16,
  // so LDS granule p of row r holds global granule p ^ ((r>>1)&3).
  {
    const int srow = lane >> 2;
    const int sg   = ((lane & 3) ^ ((srow >> 1) & 3)) << 3;   // halves
    const _Float16* Ag = Ah + (size_t)(row0 + wid * 16 + srow) * D + sg;
    _Float16* Al = Af + wid * 16 * 32;
    #pragma unroll
    for (int kt = 0; kt < 8; ++kt)
      gload_lds16(Ag + kt * 32, Al + kt * 64 * 32);
  }
  __syncthreads();

  const int cl = lane & 15;           // fragment row/col within 16
  const int q  = lane >> 4;           // quad: k-chunk selector
  const int fg = (q ^ ((cl >> 1) & 3)) << 3;           // de-swizzle granule
  const _Float16* Ab = Af + cl * 32 + fg;
  const _Float16* Bp = Vh + (size_t)(col0 + cl) * D + q * 8;  // + j*16*D + kt*32

  f32x4 acc[4][4];
  #pragma unroll
  for (int i = 0; i < 4; ++i)
    #pragma unroll
    for (int j = 0; j < 4; ++j) acc[i][j] = (f32x4){0.f, 0.f, 0.f, 0.f};

  // prefetch kt=0
  half8 bn[4], afn[4];
  #pragma unroll
  for (int j = 0; j < 4; ++j) bn[j] = *(const half8*)(Bp + (size_t)j * 16 * D);
  #pragma unroll
  for (int i = 0; i < 4; ++i) afn[i] = *(const half8*)(Ab + i * 512);

  #pragma unroll 1                    // keep live set bounded (R6 lesson)
  for (int kt = 0; kt < 8; ++kt) {
    half8 b[4], af[4];
    #pragma unroll
    for (int j = 0; j < 4; ++j) b[j] = bn[j];
    #pragma unroll
    for (int i = 0; i < 4; ++i) af[i] = afn[i];
    if (kt < 7) {                     // prefetch kt+1 while MFMA runs on kt
      #pragma unroll
      for (int j = 0; j < 4; ++j)
        bn[j] = *(const half8*)(Bp + (size_t)j * 16 * D + (kt + 1) * 32);
      #pragma unroll
      for (int i = 0; i < 4; ++i)
        afn[i] = *(const half8*)(Ab + (kt + 1) * 2048 + i * 512);
    }
    #pragma unroll
    for (int i = 0; i < 4; ++i)
      #pragma unroll
      for (int j = 0; j < 4; ++j)
        acc[i][j] = __builtin_amdgcn_mfma_f32_16x16x32_f16(af[i], b[j], acc[i][j], 0, 0, 0);
  }

  // Epilogue. C/D layout: col=lane&15, row=quad*4+reg (m89/m91-verified).
  // key_f = (score+1024)*512 = (v2+1024)*512 - 1024*acc
  float Cj[4];
  #pragma unroll
  for (int j = 0; j < 4; ++j) Cj[j] = fmaf(v2[col0 + j * 16 + cl], 512.0f, 524288.0f);
  unsigned kk1[16], kk2[16];
  #pragma unroll
  for (int i = 0; i < 4; ++i)
    #pragma unroll
    for (int r = 0; r < 4; ++r) {
      const int p = i * 4 + r;
      unsigned K1 = 0xFFFFFFFFu, K2 = 0xFFFFFFFFu;
      #pragma unroll
      for (int j = 0; j < 4; ++j) {
        const unsigned key =
            ((unsigned)fmaf(-1024.0f, acc[i][j][r], Cj[j]) << 12) |
            (unsigned)(col0 + j * 16 + cl);
        K2 = min(K2, max(K1, key));
        K1 = min(K1, key);
      }
      kk1[p] = K1; kk2[p] = K2;
    }
  // butterfly top-2 merge across the 16 col-holder lanes -> per-wave top-2
  #pragma unroll
  for (int p = 0; p < 16; ++p) {
    unsigned k1 = kk1[p], k2 = kk2[p];
    #pragma unroll
    for (int mask = 1; mask <= 8; mask <<= 1) {
      const unsigned o1 = (unsigned)__shfl_xor((int)k1, mask);
      const unsigned o2 = (unsigned)__shfl_xor((int)k2, mask);
      k2 = min(min(k2, o2), max(k1, o1));
      k1 = min(k1, o1);
    }
    kk1[p] = k1; kk2[p] = k2;
  }
  if (cl == 0) {                      // 4 lanes (q=0..3) hold rows q*4+(p&3)
    #pragma unroll
    for (int p = 0; p < 16; ++p) {
      const int rl = (p >> 2) * 16 + q * 4 + (p & 3);
      pk1[(size_t)grp * M + row0 + rl] = kk1[p];
      pk2[(size_t)grp * M + row0 + rl] = kk2[p];
    }
  }
}

// ---------------------------------------------------------------------------
// Kernel 3: merge NSPLIT partials -> token; flagged patches emit fp64-rescore
// candidate pairs (second streaming pass, L2-hot). Inits minkey.
// ---------------------------------------------------------------------------
__global__ __launch_bounds__(256) void reduce_gather_kernel(
    const unsigned* __restrict__ pk1, const unsigned* __restrict__ pk2,
    float* __restrict__ tok, unsigned long long* __restrict__ minkey,
    unsigned* __restrict__ pairs, int* __restrict__ paircount) {
  const int m = blockIdx.x * 256 + threadIdx.x;
  unsigned K1 = 0xFFFFFFFFu, K2 = 0xFFFFFFFFu;
  for (int s = 0; s < NSPLIT; ++s) {
    const unsigned b1 = pk1[(size_t)s * M + m];
    const unsigned b2 = pk2[(size_t)s * M + m];
    K2 = min(min(K2, b2), max(K1, b1));
    K1 = min(K1, b1);
  }
  tok[m] = (float)(K1 & 4095u);
  minkey[m] = 0xFFFFFFFFFFFFFFFFull;
  if ((int)(K2 >> 12) - (int)(K1 >> 12) <= QMARGIN) {
    const int th = (int)(K1 >> 12) + QMARGIN;
    int cnt = 0;
    for (int s = 0; s < NSPLIT; ++s) {
      const unsigned b1 = pk1[(size_t)s * M + m];
      const unsigned b2 = pk2[(size_t)s * M + m];
      cnt += ((int)(b2 >> 12) <= th) ? 64
           : (((int)(b1 >> 12) <= th) ? 1 : 0);
    }
    int base = atomicAdd(paircount, cnt);
    if (base + cnt <= PAIR_CAP) {
      const unsigned mh = (unsigned)m << 12;
      for (int s = 0; s < NSPLIT; ++s) {
        const unsigned b1 = pk1[(size_t)s * M + m];
        const unsigned b2 = pk2[(size_t)s * M + m];
        if ((int)(b2 >> 12) <= th) {          // group may hide a 3rd contender
          for (int r = 0; r < 64; ++r) pairs[base + r] = mh | (unsigned)(s * 64 + r);
          base += 64;
        } else if ((int)(b1 >> 12) <= th) {   // only stored winner qualifies
          pairs[base++] = mh | (b1 & 4095u);
        }
      }
    }
  }
}

// ---------------------------------------------------------------------------
// Kernel 4: exact fp64 rescore, one wave per pair, single pass.
// key = (bits(d2) & ~0xFFF) | row: atomicMin = argmin with low-index
// tie-break; 12 dropped mantissa bits = ~1e-9 abs tolerance (safe).
// ---------------------------------------------------------------------------
__global__ __launch_bounds__(256) void refine_score(
    const float* __restrict__ patches, const float* __restrict__ vocab,
    const unsigned* __restrict__ pairs, const int* __restrict__ paircount,
    unsigned long long* __restrict__ minkey) {
  const int lane = threadIdx.x & 63;
  const int gw = (blockIdx.x * 256 + threadIdx.x) >> 6;
  const int nw = (gridDim.x * 256) >> 6;
  int np = *paircount;
  if (np > PAIR_CAP) np = PAIR_CAP;
  for (int i = gw; i < np; i += nw) {
    const unsigned pr = pairs[i];
    const int m = pr >> 12, row = pr & 4095;
    const float4 pv = *(const float4*)(patches + (size_t)m * D + (lane << 2));
    const float4 vv = *(const float4*)(vocab + (size_t)row * D + (lane << 2));
    double acc = 0.0, df;
    df = (double)pv.x - (double)vv.x; acc = fma(df, df, acc);
    df = (double)pv.y - (double)vv.y; acc = fma(df, df, acc);
    df = (double)pv.z - (double)vv.z; acc = fma(df, df, acc);
    df = (double)pv.w - (double)vv.w; acc = fma(df, df, acc);
    #pragma unroll
    for (int off = 32; off > 0; off >>= 1) acc += __shfl_down(acc, off);
    if (lane == 0) {
      const unsigned long long key =
          ((unsigned long long)__double_as_longlong(acc) & ~0xFFFull) | (unsigned)row;
      atomicMin(&minkey[m], key);
    }
  }
}

// ---------------------------------------------------------------------------
// Kernel 5: write refined tokens (grid-stride over pairs; redundant same-value
// writes per flagged patch are benign).
// ---------------------------------------------------------------------------
__global__ __launch_bounds__(256) void refine_final(
    const unsigned* __restrict__ pairs, const int* __restrict__ paircount,
    const unsigned long long* __restrict__ minkey, float* __restrict__ tok) {
  int np = *paircount;
  if (np > PAIR_CAP) np = PAIR_CAP;
  for (int i = blockIdx.x * 256 + threadIdx.x; i < np; i += gridDim.x * 256) {
    const int m = pairs[i] >> 12;
    tok[m] = (float)(unsigned)(minkey[m] & 4095ull);
  }
}

// ---------------------------------------------------------------------------
extern "C" void kernel_launch(void* const* d_in, const int* in_sizes, int n_in,
                              void* d_out, int out_size, void* d_ws, size_t ws_size,
                              hipStream_t stream) {
  const float* images = (const float*)d_in[0];   // [64,256,256]
  const float* vocab  = (const float*)d_in[1];   // [4096,256]
  float* out     = (float*)d_out;
  float* patches = out;            // M*D floats
  float* tokens  = out + (size_t)M * D;

  // workspace layout (bytes):
  // Ah 8MB | Vh 2MB | v2 16KB | pk1 4MB | pk2 4MB | minkey 128KB |
  // paircount 64B | pairs 4MB   (~22.3 MB)
  char* ws = (char*)d_ws;
  _Float16* Ah       = (_Float16*)(ws);
  _Float16* Vh       = (_Float16*)(ws + 8388608);
  float*    v2       = (float*)   (ws + 10485760);
  unsigned* pk1      = (unsigned*)(ws + 10502144);
  unsigned* pk2      = (unsigned*)(ws + 14696448);
  unsigned long long* minkey = (unsigned long long*)(ws + 18890752);
  int*      paircount= (int*)     (ws + 19021824);
  unsigned* pairs    = (unsigned*)(ws + 19021888);

  prep_kernel<<<4096 + 1024, 256, 0, stream>>>(images, vocab, patches, Ah,
                                               Vh, v2, paircount);
  gemm_score_kernel<<<dim3(M / 64, V / 256), 256, 0, stream>>>(Ah, Vh, v2, pk1, pk2);
  reduce_gather_kernel<<<M / 256, 256, 0, stream>>>(pk1, pk2, tokens, minkey,
                                                    pairs, paircount);
  refine_score<<<512, 256, 0, stream>>>(patches, vocab, pairs, paircount, minkey);
  refine_final<<<64, 256, 0, stream>>>(pairs, paircount, minkey, tokens);
}

// Round 11
// 163.565 us; speedup vs baseline: 1.1358x; 1.1358x over previous
//
#include <hip/hip_runtime.h>
#include <math.h>

// Problem: images [64,256,256] f32 -> patches [16384][256] f32 (identity perm)
//          tokens [16384] = argmin_v ||patch - vocab[v]||^2, vocab [4096][256] f32
#define PS      16
#define D       256
#define V       4096
#define M       16384
#define NSPLIT  64              // V / 64 column groups (per-wave partials)
#define PAIR_CAP 1048576
// Scores packed as u32 keys: q = (u32)((s + 1024) * 512)  (20 bits), key =
// (q << 12) | col. min() on keys = argmin with lowest-index tie-break.
// fp16 score-diff error sigma ~3e-2; QMARGIN 130 quanta (=0.254) is ~8 sigma
// incl. trunc slack. Flagged (~4%) get exact fp64 on a candidate set provably
// containing the argmin.
#define QMARGIN 130

typedef _Float16 half8 __attribute__((ext_vector_type(8)));
typedef _Float16 half4 __attribute__((ext_vector_type(4)));
typedef float    f32x4 __attribute__((ext_vector_type(4)));

__device__ __forceinline__ void gload_lds16(const void* g, void* l) {
  __builtin_amdgcn_global_load_lds(
      (const __attribute__((address_space(1))) unsigned int*)g,
      (__attribute__((address_space(3))) unsigned int*)l, 16, 0, 0);
}

// Fragment-major layouts (halves):
//  Ah2[rowblk(256)][kt(8)][i(4)][q(4)][cl(16)][8] : row = rowblk*64+i*16+cl,
//      k = kt*32 + q*8 + h.   idx = rowblk*16384 + kt*2048 + i*512 + q*128 + cl*8 + h
//  Vh2[sp(16)][kt(8)][jb(16)][q(4)][cl(16)][8]    : col = sp*256+jb*16+cl,
//      k = kt*32 + q*8 + h.   idx = sp*65536 + kt*8192 + jb*512 + q*128 + cl*8 + h

// ---------------------------------------------------------------------------
// Kernel 1: fused prep. Blocks [0,4096): patchify (float4) + fragment-major
// fp16 copy. Blocks [4096,5120): vocab fragment-major fp16 + v2.
// ---------------------------------------------------------------------------
__global__ __launch_bounds__(256) void prep_kernel(
    const float* __restrict__ img, const float* __restrict__ vocab,
    float* __restrict__ outp, _Float16* __restrict__ Ah2,
    _Float16* __restrict__ Vh2, float* __restrict__ v2,
    int* __restrict__ paircount) {
  if (blockIdx.x < 4096) {
    if (blockIdx.x == 0 && threadIdx.x == 0) *paircount = 0;
    const int t  = blockIdx.x * 256 + threadIdx.x;   // M*D/4 threads
    const int o4 = t << 2;
    const int m   = o4 >> 8;           // global patch index
    const int d   = o4 & 255;          // k (multiple of 4)
    const int b   = m >> 8;
    const int n   = m & 255;
    const int py = n >> 4, px = n & 15, i = d >> 4, j = d & 15;
    const float4 v = *(const float4*)(img + (b << 16) + ((py * PS + i) << 8) + px * PS + j);
    *(float4*)(outp + o4) = v;
    half4 h = { (_Float16)v.x, (_Float16)v.y, (_Float16)v.z, (_Float16)v.w };
    const int fa = (m >> 6) * 16384 + (d >> 5) * 2048 + ((m >> 4) & 3) * 512 +
                   ((d >> 3) & 3) * 128 + (m & 15) * 8 + (d & 7);
    *(half4*)(Ah2 + fa) = h;
  } else {
    const int gtid = (blockIdx.x - 4096) * 256 + threadIdx.x;
    const int c    = gtid >> 6;        // vocab row
    const int lane = gtid & 63;
    const int d0   = lane << 2;        // k (multiple of 4)
    const float4 v = *(const float4*)(vocab + (size_t)c * D + d0);
    half4 h = { (_Float16)v.x, (_Float16)v.y, (_Float16)v.z, (_Float16)v.w };
    const int fv = (c >> 8) * 65536 + (d0 >> 5) * 8192 + ((c >> 4) & 15) * 512 +
                   ((d0 >> 3) & 3) * 128 + (c & 15) * 8 + (d0 & 7);
    *(half4*)(Vh2 + fv) = h;
    float s = v.x * v.x + v.y * v.y + v.z * v.z + v.w * v.w;
    #pragma unroll
    for (int off = 32; off > 0; off >>= 1) s += __shfl_down(s, off);
    if (lane == 0) v2[c] = s;
  }
}

// ---------------------------------------------------------------------------
// Kernel 2: fp16 MFMA score GEMM on fragment-major inputs.
// Block = 64 rows x 256 cols; wave = 64 rows x 64 cols (acc[4][4], 128 MFMA).
// A tile (32KB) LDS-resident via LINEAR global_load_lds: per-lane global addr
// (lane*16B, contiguous) -> HW scatters to LDS base + lane*16 = linear copy.
// (R10 bug: wave-uniform global addr broadcast the same 16B to all lanes.)
// B fragments direct global->VGPR: one v-offset + immediate j-offsets,
// 64 lanes read a contiguous 1KB per instruction (perfect coalescing).
// K-loop VALU ~= 2 pointer adds. __launch_bounds__(256,4): 128-reg cap ->
// 4 waves/SIMD (R9 ran 3; occupancy was a co-limiter, reg file incl. AGPR).
// ---------------------------------------------------------------------------
__global__ __launch_bounds__(256, 4) void gemm_score_kernel(
    const _Float16* __restrict__ Ah2,  // fragment-major, see layout above
    const _Float16* __restrict__ Vh2,
    const float* __restrict__ v2,
    unsigned* __restrict__ pk1, unsigned* __restrict__ pk2) {
  __shared__ __align__(16) _Float16 Af[8 * 64 * 32];  // 32 KB, same layout as Ah2 blk

  const int tid  = threadIdx.x;
  const int lane = tid & 63;
  const int wid  = tid >> 6;
  const int rowblk = blockIdx.x;
  const int sp     = blockIdx.y;            // 256-col split
  const int row0 = rowblk * 64;
  const int col0 = sp * 256 + wid * 64;     // this wave's 64 cols
  const int grp  = sp * 4 + wid;            // 64-col group id

  // ---- stage A tile: 8 x (64 lanes x 16B contiguous), one barrier ----
  {
    const _Float16* src = Ah2 + (size_t)rowblk * 16384 + wid * 4096 + lane * 8;
    _Float16* dst = Af + wid * 4096;        // wave-uniform; HW adds lane*16B
    #pragma unroll
    for (int t = 0; t < 8; ++t)
      gload_lds16(src + t * 512, dst + t * 512);
  }
  __syncthreads();

  const int cl = lane & 15;           // fragment row/col within 16
  const int q  = lane >> 4;           // quad: k-chunk selector
  const _Float16* Ak = Af + q * 128 + cl * 8;                       // + kt*2048 + i*512
  const _Float16* Bk = Vh2 + (size_t)sp * 65536 + wid * 2048 + q * 128 + cl * 8;  // + kt*8192 + j*512

  f32x4 acc[4][4];
  #pragma unroll
  for (int i = 0; i < 4; ++i)
    #pragma unroll
    for (int j = 0; j < 4; ++j) acc[i][j] = (f32x4){0.f, 0.f, 0.f, 0.f};

  #pragma unroll 1                    // bound live set (R6 lesson)
  for (int kt = 0; kt < 8; ++kt) {
    half8 b[4], af[4];
    #pragma unroll
    for (int j = 0; j < 4; ++j) b[j] = *(const half8*)(Bk + j * 512);
    #pragma unroll
    for (int i = 0; i < 4; ++i) af[i] = *(const half8*)(Ak + i * 512);
    Bk += 8192; Ak += 2048;
    #pragma unroll
    for (int i = 0; i < 4; ++i)
      #pragma unroll
      for (int j = 0; j < 4; ++j)
        acc[i][j] = __builtin_amdgcn_mfma_f32_16x16x32_f16(af[i], b[j], acc[i][j], 0, 0, 0);
  }

  // Epilogue. C/D layout: col=lane&15, row=quad*4+reg (m89/m91-verified).
  // key_f = (score+1024)*512 = (v2+1024)*512 - 1024*acc
  float Cj[4];
  #pragma unroll
  for (int j = 0; j < 4; ++j) Cj[j] = fmaf(v2[col0 + j * 16 + cl], 512.0f, 524288.0f);
  unsigned kk1[16], kk2[16];
  #pragma unroll
  for (int i = 0; i < 4; ++i)
    #pragma unroll
    for (int r = 0; r < 4; ++r) {
      const int p = i * 4 + r;
      unsigned K1 = 0xFFFFFFFFu, K2 = 0xFFFFFFFFu;
      #pragma unroll
      for (int j = 0; j < 4; ++j) {
        const unsigned key =
            ((unsigned)fmaf(-1024.0f, acc[i][j][r], Cj[j]) << 12) |
            (unsigned)(col0 + j * 16 + cl);
        K2 = min(K2, max(K1, key));
        K1 = min(K1, key);
      }
      kk1[p] = K1; kk2[p] = K2;
    }
  // butterfly top-2 merge across the 16 col-holder lanes -> per-wave top-2
  #pragma unroll
  for (int p = 0; p < 16; ++p) {
    unsigned k1 = kk1[p], k2 = kk2[p];
    #pragma unroll
    for (int mask = 1; mask <= 8; mask <<= 1) {
      const unsigned o1 = (unsigned)__shfl_xor((int)k1, mask);
      const unsigned o2 = (unsigned)__shfl_xor((int)k2, mask);
      k2 = min(min(k2, o2), max(k1, o1));
      k1 = min(k1, o1);
    }
    kk1[p] = k1; kk2[p] = k2;
  }
  if (cl == 0) {                      // 4 lanes (q=0..3) hold rows q*4+(p&3)
    #pragma unroll
    for (int p = 0; p < 16; ++p) {
      const int rl = (p >> 2) * 16 + q * 4 + (p & 3);
      pk1[(size_t)grp * M + row0 + rl] = kk1[p];
      pk2[(size_t)grp * M + row0 + rl] = kk2[p];
    }
  }
}

// ---------------------------------------------------------------------------
// Kernel 3: merge NSPLIT partials -> token; flagged patches emit fp64-rescore
// candidate pairs (second streaming pass, L2-hot). Inits minkey.
// ---------------------------------------------------------------------------
__global__ __launch_bounds__(256) void reduce_gather_kernel(
    const unsigned* __restrict__ pk1, const unsigned* __restrict__ pk2,
    float* __restrict__ tok, unsigned long long* __restrict__ minkey,
    unsigned* __restrict__ pairs, int* __restrict__ paircount) {
  const int m = blockIdx.x * 256 + threadIdx.x;
  unsigned K1 = 0xFFFFFFFFu, K2 = 0xFFFFFFFFu;
  for (int s = 0; s < NSPLIT; ++s) {
    const unsigned b1 = pk1[(size_t)s * M + m];
    const unsigned b2 = pk2[(size_t)s * M + m];
    K2 = min(min(K2, b2), max(K1, b1));
    K1 = min(K1, b1);
  }
  tok[m] = (float)(K1 & 4095u);
  minkey[m] = 0xFFFFFFFFFFFFFFFFull;
  if ((int)(K2 >> 12) - (int)(K1 >> 12) <= QMARGIN) {
    const int th = (int)(K1 >> 12) + QMARGIN;
    int cnt = 0;
    for (int s = 0; s < NSPLIT; ++s) {
      const unsigned b1 = pk1[(size_t)s * M + m];
      const unsigned b2 = pk2[(size_t)s * M + m];
      cnt += ((int)(b2 >> 12) <= th) ? 64
           : (((int)(b1 >> 12) <= th) ? 1 : 0);
    }
    int base = atomicAdd(paircount, cnt);
    if (base + cnt <= PAIR_CAP) {
      const unsigned mh = (unsigned)m << 12;
      for (int s = 0; s < NSPLIT; ++s) {
        const unsigned b1 = pk1[(size_t)s * M + m];
        const unsigned b2 = pk2[(size_t)s * M + m];
        if ((int)(b2 >> 12) <= th) {          // group may hide a 3rd contender
          for (int r = 0; r < 64; ++r) pairs[base + r] = mh | (unsigned)(s * 64 + r);
          base += 64;
        } else if ((int)(b1 >> 12) <= th) {   // only stored winner qualifies
          pairs[base++] = mh | (b1 & 4095u);
        }
      }
    }
  }
}

// ---------------------------------------------------------------------------
// Kernel 4: exact fp64 rescore, one wave per pair, single pass.
// key = (bits(d2) & ~0xFFF) | row: atomicMin = argmin with low-index
// tie-break; 12 dropped mantissa bits = ~1e-9 abs tolerance (safe).
// ---------------------------------------------------------------------------
__global__ __launch_bounds__(256) void refine_score(
    const float* __restrict__ patches, const float* __restrict__ vocab,
    const unsigned* __restrict__ pairs, const int* __restrict__ paircount,
    unsigned long long* __restrict__ minkey) {
  const int lane = threadIdx.x & 63;
  const int gw = (blockIdx.x * 256 + threadIdx.x) >> 6;
  const int nw = (gridDim.x * 256) >> 6;
  int np = *paircount;
  if (np > PAIR_CAP) np = PAIR_CAP;
  for (int i = gw; i < np; i += nw) {
    const unsigned pr = pairs[i];
    const int m = pr >> 12, row = pr & 4095;
    const float4 pv = *(const float4*)(patches + (size_t)m * D + (lane << 2));
    const float4 vv = *(const float4*)(vocab + (size_t)row * D + (lane << 2));
    double acc = 0.0, df;
    df = (double)pv.x - (double)vv.x; acc = fma(df, df, acc);
    df = (double)pv.y - (double)vv.y; acc = fma(df, df, acc);
    df = (double)pv.z - (double)vv.z; acc = fma(df, df, acc);
    df = (double)pv.w - (double)vv.w; acc = fma(df, df, acc);
    #pragma unroll
    for (int off = 32; off > 0; off >>= 1) acc += __shfl_down(acc, off);
    if (lane == 0) {
      const unsigned long long key =
          ((unsigned long long)__double_as_longlong(acc) & ~0xFFFull) | (unsigned)row;
      atomicMin(&minkey[m], key);
    }
  }
}

// ---------------------------------------------------------------------------
// Kernel 5: write refined tokens (grid-stride over pairs; redundant same-value
// writes per flagged patch are benign).
// ---------------------------------------------------------------------------
__global__ __launch_bounds__(256) void refine_final(
    const unsigned* __restrict__ pairs, const int* __restrict__ paircount,
    const unsigned long long* __restrict__ minkey, float* __restrict__ tok) {
  int np = *paircount;
  if (np > PAIR_CAP) np = PAIR_CAP;
  for (int i = blockIdx.x * 256 + threadIdx.x; i < np; i += gridDim.x * 256) {
    const int m = pairs[i] >> 12;
    tok[m] = (float)(unsigned)(minkey[m] & 4095ull);
  }
}

// ---------------------------------------------------------------------------
extern "C" void kernel_launch(void* const* d_in, const int* in_sizes, int n_in,
                              void* d_out, int out_size, void* d_ws, size_t ws_size,
                              hipStream_t stream) {
  const float* images = (const float*)d_in[0];   // [64,256,256]
  const float* vocab  = (const float*)d_in[1];   // [4096,256]
  float* out     = (float*)d_out;
  float* patches = out;            // M*D floats
  float* tokens  = out + (size_t)M * D;

  // workspace layout (bytes):
  // Ah2 8MB | Vh2 2MB | v2 16KB | pk1 4MB | pk2 4MB | minkey 128KB |
  // paircount 64B | pairs 4MB   (~22.3 MB)
  char* ws = (char*)d_ws;
  _Float16* Ah2      = (_Float16*)(ws);
  _Float16* Vh2      = (_Float16*)(ws + 8388608);
  float*    v2       = (float*)   (ws + 10485760);
  unsigned* pk1      = (unsigned*)(ws + 10502144);
  unsigned* pk2      = (unsigned*)(ws + 14696448);
  unsigned long long* minkey = (unsigned long long*)(ws + 18890752);
  int*      paircount= (int*)     (ws + 19021824);
  unsigned* pairs    = (unsigned*)(ws + 19021888);

  prep_kernel<<<4096 + 1024, 256, 0, stream>>>(images, vocab, patches, Ah2,
                                               Vh2, v2, paircount);
  gemm_score_kernel<<<dim3(M / 64, V / 256), 256, 0, stream>>>(Ah2, Vh2, v2, pk1, pk2);
  reduce_gather_kernel<<<M / 256, 256, 0, stream>>>(pk1, pk2, tokens, minkey,
                                                    pairs, paircount);
  refine_score<<<512, 256, 0, stream>>>(patches, vocab, pairs, paircount, minkey);
  refine_final<<<64, 256, 0, stream>>>(pairs, paircount, minkey, tokens);
}